// Round 1
// baseline (447.183 us; speedup 1.0000x reference)
//
#include <hip/hip_runtime.h>

#define LRELU(x) ((x) > 0.f ? (x) : 0.2f * (x))

__device__ __forceinline__ float wmaxf(float v) {
#pragma unroll
  for (int o = 32; o; o >>= 1) v = fmaxf(v, __shfl_xor(v, o));
  return v;
}
__device__ __forceinline__ float wsumf(float v) {
#pragma unroll
  for (int o = 32; o; o >>= 1) v += __shfl_xor(v, o);
  return v;
}

// ---- edge dtype detection: int64 arrives as [lo,hi] word pairs, hi==0 always ----
__global__ void detect_i64_kernel(const int* __restrict__ w, int* __restrict__ flag) {
  if (threadIdx.x == 0 && blockIdx.x == 0) {
    int all0 = 1;
    for (int j = 0; j < 128; j++)
      if (w[2 * j + 1] != 0) { all0 = 0; break; }
    *flag = all0;  // 1 => int64 layout, 0 => int32 layout
  }
}

__device__ __forceinline__ int edge_at(const void* ei, long long idx, int is64) {
  if (is64) return (int)((const long long*)ei)[idx];
  return ((const int*)ei)[idx];
}

// ---- CSR build ----
__global__ void hist_kernel(const void* __restrict__ ei, const int* __restrict__ flag,
                            int* __restrict__ counts, int E, int N) {
  int i = blockIdx.x * blockDim.x + threadIdx.x;
  int tot = E + N;
  if (i >= tot) return;
  int f = *flag;
  int d = (i < E) ? edge_at(ei, (long long)E + i, f) : (i - E);
  atomicAdd(&counts[d], 1);
}

__global__ __launch_bounds__(512) void scan1_kernel(const int* __restrict__ counts,
                                                    int* __restrict__ partial,
                                                    int* __restrict__ blocksums, int N) {
  __shared__ int sm[1024];
  int t = threadIdx.x;
  int i = blockIdx.x * 512 + t;
  int v = (i < N) ? counts[i] : 0;
  int* cur = sm;
  int* nxt = sm + 512;
  cur[t] = v;
  __syncthreads();
  for (int off = 1; off < 512; off <<= 1) {
    int x = cur[t];
    if (t >= off) x += cur[t - off];
    nxt[t] = x;
    __syncthreads();
    int* tmp = cur; cur = nxt; nxt = tmp;
  }
  if (i < N) partial[i] = cur[t];
  if (t == 511) blocksums[blockIdx.x] = cur[511];
}

__global__ __launch_bounds__(512) void scan2_kernel(int* __restrict__ bs, int B) {
  __shared__ int sm[1024];
  int t = threadIdx.x;
  int v = (t < B) ? bs[t] : 0;
  int* cur = sm;
  int* nxt = sm + 512;
  cur[t] = v;
  __syncthreads();
  for (int off = 1; off < 512; off <<= 1) {
    int x = cur[t];
    if (t >= off) x += cur[t - off];
    nxt[t] = x;
    __syncthreads();
    int* tmp = cur; cur = nxt; nxt = tmp;
  }
  if (t < B) bs[t] = cur[t] - v;  // exclusive offsets
}

__global__ void scan3_kernel(const int* __restrict__ partial, const int* __restrict__ bs,
                             int* __restrict__ row_ptr, int* __restrict__ cursor, int N) {
  int i = blockIdx.x * blockDim.x + threadIdx.x;
  if (i == 0) { row_ptr[0] = 0; cursor[0] = 0; }
  if (i < N) {
    int v = partial[i] + bs[i >> 9];
    row_ptr[i + 1] = v;
    if (i + 1 < N) cursor[i + 1] = v;
  }
}

__global__ void scatter_kernel(const void* __restrict__ ei, const int* __restrict__ flag,
                               int* __restrict__ cursor, int* __restrict__ srcs, int E, int N) {
  int i = blockIdx.x * blockDim.x + threadIdx.x;
  int tot = E + N;
  if (i >= tot) return;
  int f = *flag;
  int s, d;
  if (i < E) {
    s = edge_at(ei, i, f);
    d = edge_at(ei, (long long)E + i, f);
  } else {
    s = i - E; d = s;
  }
  int pos = atomicAdd(&cursor[d], 1);
  srcs[pos] = s;
}

// ---- fp32 tiled GEMM: C[M,N] = A[M,K] @ B[K,N]; N,K multiples of 64/16 ----
__global__ __launch_bounds__(256) void gemm_kernel(const float* __restrict__ A,
                                                   const float* __restrict__ B,
                                                   float* __restrict__ C, int M, int N, int K) {
  __shared__ float As[16][64];
  __shared__ float Bs[16][64];
  int tid = threadIdx.x;
  int bm = blockIdx.y * 64;
  int bn = blockIdx.x * 64;
  int tm = (tid >> 4) * 4;
  int tn = (tid & 15) * 4;
  int ar = tid >> 2;
  int ac = (tid & 3) * 4;
  int br = tid >> 4;
  int bc = (tid & 15) * 4;
  float acc[4][4] = {};
  for (int k0 = 0; k0 < K; k0 += 16) {
    float4 av = make_float4(0.f, 0.f, 0.f, 0.f);
    int arow = bm + ar;
    if (arow < M) av = *(const float4*)(A + (long long)arow * K + k0 + ac);
    As[ac + 0][ar] = av.x; As[ac + 1][ar] = av.y;
    As[ac + 2][ar] = av.z; As[ac + 3][ar] = av.w;
    *(float4*)&Bs[br][bc] = *(const float4*)(B + (long long)(k0 + br) * N + bn + bc);
    __syncthreads();
#pragma unroll
    for (int k = 0; k < 16; k++) {
      float ra[4], rb[4];
#pragma unroll
      for (int m = 0; m < 4; m++) ra[m] = As[k][tm + m];
#pragma unroll
      for (int n = 0; n < 4; n++) rb[n] = Bs[k][tn + n];
#pragma unroll
      for (int m = 0; m < 4; m++)
#pragma unroll
        for (int n = 0; n < 4; n++) acc[m][n] = fmaf(ra[m], rb[n], acc[m][n]);
    }
    __syncthreads();
  }
  for (int m = 0; m < 4; m++) {
    int r = bm + tm + m;
    if (r < M) {
      float4 o = make_float4(acc[m][0], acc[m][1], acc[m][2], acc[m][3]);
      *(float4*)(C + (long long)r * N + bn + tn) = o;
    }
  }
}

// ---- per-node alpha_s / alpha_d (wave per node, lane = channel) ----
__global__ __launch_bounds__(256) void alpha_kernel(const float* __restrict__ h,
                                                    const float* __restrict__ asrc,
                                                    const float* __restrict__ adst,
                                                    float* __restrict__ as, float* __restrict__ ad,
                                                    int N, int H) {
  int gw = (blockIdx.x * 256 + threadIdx.x) >> 6;
  int lane = threadIdx.x & 63;
  if (gw >= N) return;
  const float* hp = h + (size_t)gw * H * 64;
  for (int hh = 0; hh < H; hh++) {
    float v = hp[hh * 64 + lane];
    float s = wsumf(v * asrc[hh * 64 + lane]);
    float d = wsumf(v * adst[hh * 64 + lane]);
    if (lane == 0) {
      as[(size_t)gw * H + hh] = s;
      ad[(size_t)gw * H + hh] = d;
    }
  }
}

// ---- layer-1 aggregation: H=4, C=64, fused bias + ReLU. Wave per dst node. ----
__global__ __launch_bounds__(256) void gat_agg_h4(const float* __restrict__ h,
                                                  const float* __restrict__ as,
                                                  const float* __restrict__ ad,
                                                  const int* __restrict__ row_ptr,
                                                  const int* __restrict__ srcs,
                                                  const float* __restrict__ bias,
                                                  float* __restrict__ out, int N) {
  int gw = (blockIdx.x * 256 + threadIdx.x) >> 6;
  int lane = threadIdx.x & 63;
  if (gw >= N) return;
  int beg = row_ptr[gw], end = row_ptr[gw + 1];
  const float4 adv = *(const float4*)(ad + (size_t)gw * 4);
  float m0 = -1e30f, m1 = -1e30f, m2 = -1e30f, m3 = -1e30f;
  for (int j = beg + lane; j < end; j += 64) {
    int s = srcs[j];
    float4 a = *(const float4*)(as + (size_t)s * 4);
    m0 = fmaxf(m0, LRELU(a.x + adv.x));
    m1 = fmaxf(m1, LRELU(a.y + adv.y));
    m2 = fmaxf(m2, LRELU(a.z + adv.z));
    m3 = fmaxf(m3, LRELU(a.w + adv.w));
  }
  m0 = wmaxf(m0); m1 = wmaxf(m1); m2 = wmaxf(m2); m3 = wmaxf(m3);
  float s0 = 0.f, s1 = 0.f, s2 = 0.f, s3 = 0.f;
  for (int j = beg + lane; j < end; j += 64) {
    int s = srcs[j];
    float4 a = *(const float4*)(as + (size_t)s * 4);
    s0 += __expf(LRELU(a.x + adv.x) - m0);
    s1 += __expf(LRELU(a.y + adv.y) - m1);
    s2 += __expf(LRELU(a.z + adv.z) - m2);
    s3 += __expf(LRELU(a.w + adv.w) - m3);
  }
  s0 = wsumf(s0); s1 = wsumf(s1); s2 = wsumf(s2); s3 = wsumf(s3);
  float i0 = 1.f / (s0 + 1e-16f), i1 = 1.f / (s1 + 1e-16f);
  float i2 = 1.f / (s2 + 1e-16f), i3 = 1.f / (s3 + 1e-16f);
  float acc0 = 0.f, acc1 = 0.f, acc2 = 0.f, acc3 = 0.f;
  for (int j = beg; j < end; ++j) {
    int s = srcs[j];
    float4 a = *(const float4*)(as + (size_t)s * 4);
    float al0 = __expf(LRELU(a.x + adv.x) - m0) * i0;
    float al1 = __expf(LRELU(a.y + adv.y) - m1) * i1;
    float al2 = __expf(LRELU(a.z + adv.z) - m2) * i2;
    float al3 = __expf(LRELU(a.w + adv.w) - m3) * i3;
    const float* hp = h + (size_t)s * 256;
    acc0 = fmaf(al0, hp[lane], acc0);
    acc1 = fmaf(al1, hp[64 + lane], acc1);
    acc2 = fmaf(al2, hp[128 + lane], acc2);
    acc3 = fmaf(al3, hp[192 + lane], acc3);
  }
  size_t o = (size_t)gw * 256;
  out[o + lane]        = fmaxf(acc0 + bias[lane], 0.f);
  out[o + 64 + lane]   = fmaxf(acc1 + bias[64 + lane], 0.f);
  out[o + 128 + lane]  = fmaxf(acc2 + bias[128 + lane], 0.f);
  out[o + 192 + lane]  = fmaxf(acc3 + bias[192 + lane], 0.f);
}

// ---- layer-2 aggregation: H=1, C=64, + bias (no ReLU). Wave per dst node. ----
__global__ __launch_bounds__(256) void gat_agg_h1(const float* __restrict__ h,
                                                  const float* __restrict__ as,
                                                  const float* __restrict__ ad,
                                                  const int* __restrict__ row_ptr,
                                                  const int* __restrict__ srcs,
                                                  const float* __restrict__ bias,
                                                  float* __restrict__ out, int N) {
  int gw = (blockIdx.x * 256 + threadIdx.x) >> 6;
  int lane = threadIdx.x & 63;
  if (gw >= N) return;
  int beg = row_ptr[gw], end = row_ptr[gw + 1];
  float adn = ad[gw];
  float m = -1e30f;
  for (int j = beg + lane; j < end; j += 64) {
    float e = LRELU(as[srcs[j]] + adn);
    m = fmaxf(m, e);
  }
  m = wmaxf(m);
  float ssum = 0.f;
  for (int j = beg + lane; j < end; j += 64) {
    ssum += __expf(LRELU(as[srcs[j]] + adn) - m);
  }
  ssum = wsumf(ssum);
  float inv = 1.f / (ssum + 1e-16f);
  float acc = 0.f;
  for (int j = beg; j < end; ++j) {
    int s = srcs[j];
    float al = __expf(LRELU(as[s] + adn) - m) * inv;
    acc = fmaf(al, h[(size_t)s * 64 + lane], acc);
  }
  out[(size_t)gw * 64 + lane] = acc + bias[lane];
}

extern "C" void kernel_launch(void* const* d_in, const int* in_sizes, int n_in,
                              void* d_out, int out_size, void* d_ws, size_t ws_size,
                              hipStream_t stream) {
  const float* x      = (const float*)d_in[0];
  const void*  ei     = d_in[1];
  const float* W1     = (const float*)d_in[2];
  const float* a_src1 = (const float*)d_in[3];
  const float* a_dst1 = (const float*)d_in[4];
  const float* b1     = (const float*)d_in[5];
  const float* W2     = (const float*)d_in[6];
  const float* a_src2 = (const float*)d_in[7];
  const float* a_dst2 = (const float*)d_in[8];
  const float* b2     = (const float*)d_in[9];

  const int Fin = 128;
  const int N   = in_sizes[0] / Fin;   // 50000
  const int E   = in_sizes[1] / 2;     // 800000
  const int HC1 = in_sizes[2] / Fin;   // 256
  const int Etot = E + N;

  // workspace layout
  char* w = (char*)d_ws;
  auto alloc = [&](size_t bytes) {
    void* p = (void*)w;
    w += (bytes + 255) & ~(size_t)255;
    return p;
  };
  int* counts    = (int*)alloc((size_t)N * 4);
  int* row_ptr   = (int*)alloc((size_t)(N + 1) * 4);
  int* cursor    = (int*)alloc((size_t)N * 4);
  int* partial   = (int*)alloc((size_t)N * 4);
  int* blocksums = (int*)alloc(4096);
  int* flag      = (int*)alloc(256);
  int* srcs      = (int*)alloc((size_t)Etot * 4);
  float* h1      = (float*)alloc((size_t)N * 256 * 4);
  float* out1    = (float*)alloc((size_t)N * 256 * 4);
  float* as1     = (float*)alloc((size_t)N * 4 * 4);
  float* ad1     = (float*)alloc((size_t)N * 4 * 4);
  float* h2      = (float*)alloc((size_t)N * 64 * 4);
  float* as2     = (float*)alloc((size_t)N * 4);
  float* ad2     = (float*)alloc((size_t)N * 4);

  const int SB = (N + 511) / 512;  // scan blocks (98)

  // ---- CSR build ----
  detect_i64_kernel<<<1, 64, 0, stream>>>((const int*)ei, flag);
  hipMemsetAsync(counts, 0, (size_t)N * 4, stream);
  hist_kernel<<<(Etot + 255) / 256, 256, 0, stream>>>(ei, flag, counts, E, N);
  scan1_kernel<<<SB, 512, 0, stream>>>(counts, partial, blocksums, N);
  scan2_kernel<<<1, 512, 0, stream>>>(blocksums, SB);
  scan3_kernel<<<(N + 255) / 256, 256, 0, stream>>>(partial, blocksums, row_ptr, cursor, N);
  scatter_kernel<<<(Etot + 255) / 256, 256, 0, stream>>>(ei, flag, cursor, srcs, E, N);

  // ---- layer 1 ----
  gemm_kernel<<<dim3(HC1 / 64, (N + 63) / 64), 256, 0, stream>>>(x, W1, h1, N, HC1, Fin);
  alpha_kernel<<<(N + 3) / 4, 256, 0, stream>>>(h1, a_src1, a_dst1, as1, ad1, N, 4);
  gat_agg_h4<<<(N + 3) / 4, 256, 0, stream>>>(h1, as1, ad1, row_ptr, srcs, b1, out1, N);

  // ---- layer 2 ----
  gemm_kernel<<<dim3(64 / 64, (N + 63) / 64), 256, 0, stream>>>(out1, W2, h2, N, 64, HC1);
  alpha_kernel<<<(N + 3) / 4, 256, 0, stream>>>(h2, a_src2, a_dst2, as2, ad2, N, 1);
  gat_agg_h1<<<(N + 3) / 4, 256, 0, stream>>>(h2, as2, ad2, row_ptr, srcs, b2, (float*)d_out, N);
}